// Round 1
// baseline (3248.739 us; speedup 1.0000x reference)
//
#include <hip/hip_runtime.h>

// TransformerConv x2 on MI355X.
// Inputs (fp32 unless noted): x[N,128], edge_index[2,E] (int32), edge_attr[E],
// per layer: Wq[128,128], bq[128], Wk, bk, Wv, bv, We[128], Ws, bs, x2.
// N=50000, E=800000, H=4, C=32, D=128.

#define TPB 256

// ---- order-preserving float<->uint encoding for atomic segment-max ----
__device__ __forceinline__ unsigned enc_f(float f) {
    unsigned u = __float_as_uint(f);
    return (u & 0x80000000u) ? ~u : (u | 0x80000000u);
}
__device__ __forceinline__ float dec_f(unsigned u) {
    return (u & 0x80000000u) ? __uint_as_float(u & 0x7FFFFFFFu)
                             : __uint_as_float(~u);
}

// ---- fused QKV+skip GEMM: out = x @ [Wq|Wk|Wv|Ws] + bias ----
// Block: 256 threads, RB rows. threads 0..127 -> (Wq->q, Wv->v) cols,
// threads 128..255 -> (Wk->k, Ws->skip) cols. x rows staged in LDS, broadcast.
template <int RB>
__global__ void __launch_bounds__(TPB) gemm_qkvs_k(
    const float* __restrict__ x, int n,
    const float* __restrict__ Wq, const float* __restrict__ bq,
    const float* __restrict__ Wk, const float* __restrict__ bk,
    const float* __restrict__ Wv, const float* __restrict__ bv,
    const float* __restrict__ Ws, const float* __restrict__ bs,
    float* __restrict__ outq, float* __restrict__ outk,
    float* __restrict__ outv, float* __restrict__ outs)
{
    __shared__ float xs[RB][128];
    const int row0 = blockIdx.x * RB;

    for (int i = threadIdx.x; i < RB * 32; i += TPB) {
        int r = i >> 5, c4 = (i & 31) * 4;
        int row = row0 + r;
        float4 val = make_float4(0.f, 0.f, 0.f, 0.f);
        if (row < n) val = *(const float4*)(x + (size_t)row * 128 + c4);
        *(float4*)(&xs[r][c4]) = val;
    }
    __syncthreads();

    const int tid = threadIdx.x;
    const int c = tid & 127;
    const bool lo = (tid < 128);
    const float* W0 = lo ? Wq : Wk;
    const float* b0 = lo ? bq : bk;
    float*       o0 = lo ? outq : outk;
    const float* W1 = lo ? Wv : Ws;
    const float* b1 = lo ? bv : bs;
    float*       o1 = lo ? outv : outs;

    float acc0[RB], acc1[RB];
#pragma unroll
    for (int r = 0; r < RB; ++r) { acc0[r] = 0.f; acc1[r] = 0.f; }

    for (int k4 = 0; k4 < 32; ++k4) {
        float w0[4], w1[4];
#pragma unroll
        for (int j = 0; j < 4; ++j) {
            w0[j] = W0[(k4 * 4 + j) * 128 + c];
            w1[j] = W1[(k4 * 4 + j) * 128 + c];
        }
#pragma unroll
        for (int r = 0; r < RB; ++r) {
            float4 xv = *(const float4*)(&xs[r][k4 * 4]);
            acc0[r] = fmaf(xv.x, w0[0], acc0[r]);
            acc0[r] = fmaf(xv.y, w0[1], acc0[r]);
            acc0[r] = fmaf(xv.z, w0[2], acc0[r]);
            acc0[r] = fmaf(xv.w, w0[3], acc0[r]);
            acc1[r] = fmaf(xv.x, w1[0], acc1[r]);
            acc1[r] = fmaf(xv.y, w1[1], acc1[r]);
            acc1[r] = fmaf(xv.z, w1[2], acc1[r]);
            acc1[r] = fmaf(xv.w, w1[3], acc1[r]);
        }
    }

    const float bb0 = b0[c], bb1 = b1[c];
#pragma unroll
    for (int r = 0; r < RB; ++r) {
        int row = row0 + r;
        if (row < n) {
            o0[(size_t)row * 128 + c] = acc0[r] + bb0;
            o1[(size_t)row * 128 + c] = acc1[r] + bb1;
        }
    }
}

// ---- pass A: alpha[e,h] = dot(q[dst], k[src] + ea*We) / sqrt(32); seg-max ----
// 32 lanes per edge, float4 per lane; 8-lane shuffle reduce per head.
__global__ void __launch_bounds__(TPB) edge_alpha_k(
    const float* __restrict__ q, const float* __restrict__ k,
    const int* __restrict__ src, const int* __restrict__ dst,
    const float* __restrict__ ea, const float* __restrict__ We,
    float* __restrict__ alpha, unsigned* __restrict__ amax, int E)
{
    int e = blockIdx.x * 8 + (threadIdx.x >> 5);
    if (e >= E) return;
    int t = threadIdx.x & 31;
    int s = src[e], d = dst[e];
    float a = ea[e];
    float4 qv = *(const float4*)(q + (size_t)d * 128 + t * 4);
    float4 kv = *(const float4*)(k + (size_t)s * 128 + t * 4);
    float4 wv = *(const float4*)(We + t * 4);
    float sum = qv.x * fmaf(a, wv.x, kv.x) + qv.y * fmaf(a, wv.y, kv.y) +
                qv.z * fmaf(a, wv.z, kv.z) + qv.w * fmaf(a, wv.w, kv.w);
    sum += __shfl_xor(sum, 1);
    sum += __shfl_xor(sum, 2);
    sum += __shfl_xor(sum, 4);
    if ((t & 7) == 0) {
        int h = t >> 3;
        float al = sum * 0.17677669529663687f; // 1/sqrt(32)
        alpha[(size_t)e * 4 + h] = al;
        atomicMax(&amax[(size_t)d * 4 + h], enc_f(al));
    }
}

// ---- pass B: ex = exp(alpha - amax[dst]); denom += ex ----
__global__ void __launch_bounds__(TPB) edge_exp_k(
    float* __restrict__ alpha, const int* __restrict__ dst,
    const unsigned* __restrict__ amax, float* __restrict__ denom, int E)
{
    int i = blockIdx.x * TPB + threadIdx.x;
    if (i >= E * 4) return;
    int e = i >> 2, h = i & 3;
    int d = dst[e];
    float m = dec_f(amax[(size_t)d * 4 + h]);
    float ex = __expf(alpha[i] - m);
    alpha[i] = ex;
    atomicAdd(&denom[(size_t)d * 4 + h], ex);
}

// ---- pass C: out[dst] += (v[src] + ea*We) * (ex / (denom[dst]+1e-16)) ----
__global__ void __launch_bounds__(TPB) edge_msg_k(
    const float* __restrict__ v, const int* __restrict__ src,
    const int* __restrict__ dst, const float* __restrict__ ea,
    const float* __restrict__ We, const float* __restrict__ ex,
    const float* __restrict__ denom, float* __restrict__ out, int E)
{
    int e = blockIdx.x * 8 + (threadIdx.x >> 5);
    if (e >= E) return;
    int t = threadIdx.x & 31;
    int s = src[e], d = dst[e];
    int h = t >> 3;
    float w = ex[(size_t)e * 4 + h] / (denom[(size_t)d * 4 + h] + 1e-16f);
    float a = ea[e];
    float4 vv = *(const float4*)(v + (size_t)s * 128 + t * 4);
    float4 wv = *(const float4*)(We + t * 4);
    float* op = out + (size_t)d * 128 + t * 4;
    atomicAdd(op + 0, fmaf(a, wv.x, vv.x) * w);
    atomicAdd(op + 1, fmaf(a, wv.y, vv.y) * w);
    atomicAdd(op + 2, fmaf(a, wv.z, vv.z) * w);
    atomicAdd(op + 3, fmaf(a, wv.w, vv.w) * w);
}

__global__ void __launch_bounds__(TPB) relu_k(float* __restrict__ p, int n)
{
    int i = blockIdx.x * TPB + threadIdx.x;
    if (i < n) p[i] = fmaxf(p[i], 0.f);
}

extern "C" void kernel_launch(void* const* d_in, const int* in_sizes, int n_in,
                              void* d_out, int out_size, void* d_ws, size_t ws_size,
                              hipStream_t stream)
{
    const float* x   = (const float*)d_in[0];
    const int*   ei  = (const int*)d_in[1];
    const float* ea  = (const float*)d_in[2];
    const float* Wq1 = (const float*)d_in[3];  const float* bq1 = (const float*)d_in[4];
    const float* Wk1 = (const float*)d_in[5];  const float* bk1 = (const float*)d_in[6];
    const float* Wv1 = (const float*)d_in[7];  const float* bv1 = (const float*)d_in[8];
    const float* We1 = (const float*)d_in[9];
    const float* Ws1 = (const float*)d_in[10]; const float* bs1 = (const float*)d_in[11];
    const float* Wq2 = (const float*)d_in[12]; const float* bq2 = (const float*)d_in[13];
    const float* Wk2 = (const float*)d_in[14]; const float* bk2 = (const float*)d_in[15];
    const float* Wv2 = (const float*)d_in[16]; const float* bv2 = (const float*)d_in[17];
    const float* We2 = (const float*)d_in[18];
    const float* Ws2 = (const float*)d_in[19]; const float* bs2 = (const float*)d_in[20];

    const int N = in_sizes[0] / 128;
    const int E = in_sizes[1] / 2;
    const int* src = ei;
    const int* dst = ei + E;

    float* ws    = (float*)d_ws;
    float* q     = ws;
    float* k     = q + (size_t)N * 128;
    float* v     = k + (size_t)N * 128;
    float* h     = v + (size_t)N * 128;          // layer1 out / layer2 in
    float* alpha = h + (size_t)N * 128;          // [E,4], reused as ex
    unsigned* amax = (unsigned*)(alpha + (size_t)E * 4); // [N,4]
    float* denom   = (float*)(amax + (size_t)N * 4);     // [N,4] (contiguous after amax)

    float* outf = (float*)d_out;

    const int gN    = (N + 15) / 16;
    const int gE32  = (E + 7) / 8;
    const int gEH   = (E * 4 + TPB - 1) / TPB;
    const int gRelu = (N * 128 + TPB - 1) / TPB;

    // ---------------- layer 1 ----------------
    hipMemsetAsync(amax, 0, (size_t)N * 8 * sizeof(unsigned), stream); // amax+denom
    gemm_qkvs_k<16><<<gN, TPB, 0, stream>>>(x, N, Wq1, bq1, Wk1, bk1, Wv1, bv1,
                                            Ws1, bs1, q, k, v, h);
    edge_alpha_k<<<gE32, TPB, 0, stream>>>(q, k, src, dst, ea, We1, alpha, amax, E);
    edge_exp_k<<<gEH, TPB, 0, stream>>>(alpha, dst, amax, denom, E);
    edge_msg_k<<<gE32, TPB, 0, stream>>>(v, src, dst, ea, We1, alpha, denom, h, E);
    relu_k<<<gRelu, TPB, 0, stream>>>(h, N * 128);

    // ---------------- layer 2 ----------------
    hipMemsetAsync(amax, 0, (size_t)N * 8 * sizeof(unsigned), stream);
    gemm_qkvs_k<16><<<gN, TPB, 0, stream>>>(h, N, Wq2, bq2, Wk2, bk2, Wv2, bv2,
                                            Ws2, bs2, q, k, v, outf);
    edge_alpha_k<<<gE32, TPB, 0, stream>>>(q, k, src, dst, ea, We2, alpha, amax, E);
    edge_exp_k<<<gEH, TPB, 0, stream>>>(alpha, dst, amax, denom, E);
    edge_msg_k<<<gE32, TPB, 0, stream>>>(v, src, dst, ea, We2, alpha, denom, outf, E);
    relu_k<<<gRelu, TPB, 0, stream>>>(outf, N * 128);
}

// Round 2
// 564.149 us; speedup vs baseline: 5.7587x; 5.7587x over previous
//
#include <hip/hip_runtime.h>

// TransformerConv x2 on MI355X — gather formulation.
// Per layer: fused QKV+skip GEMM, then per-dst-node online-softmax gather
// (one wave per node) fused with skip+ReLU. CSR built on device per call.
// N=50000, E=800000, H=4, C=32, D=128.

#define TPB 256

// ---- fused QKV+skip GEMM: out = x @ [Wq|Wk|Wv|Ws] + bias ----
template <int RB>
__global__ void __launch_bounds__(TPB) gemm_qkvs_k(
    const float* __restrict__ x, int n,
    const float* __restrict__ Wq, const float* __restrict__ bq,
    const float* __restrict__ Wk, const float* __restrict__ bk,
    const float* __restrict__ Wv, const float* __restrict__ bv,
    const float* __restrict__ Ws, const float* __restrict__ bs,
    float* __restrict__ outq, float* __restrict__ outk,
    float* __restrict__ outv, float* __restrict__ outs)
{
    __shared__ float xs[RB][128];
    const int row0 = blockIdx.x * RB;

    for (int i = threadIdx.x; i < RB * 32; i += TPB) {
        int r = i >> 5, c4 = (i & 31) * 4;
        int row = row0 + r;
        float4 val = make_float4(0.f, 0.f, 0.f, 0.f);
        if (row < n) val = *(const float4*)(x + (size_t)row * 128 + c4);
        *(float4*)(&xs[r][c4]) = val;
    }
    __syncthreads();

    const int tid = threadIdx.x;
    const int c = tid & 127;
    const bool lo = (tid < 128);
    const float* W0 = lo ? Wq : Wk;
    const float* b0 = lo ? bq : bk;
    float*       o0 = lo ? outq : outk;
    const float* W1 = lo ? Wv : Ws;
    const float* b1 = lo ? bv : bs;
    float*       o1 = lo ? outv : outs;

    float acc0[RB], acc1[RB];
#pragma unroll
    for (int r = 0; r < RB; ++r) { acc0[r] = 0.f; acc1[r] = 0.f; }

    for (int k4 = 0; k4 < 32; ++k4) {
        float w0[4], w1[4];
#pragma unroll
        for (int j = 0; j < 4; ++j) {
            w0[j] = W0[(k4 * 4 + j) * 128 + c];
            w1[j] = W1[(k4 * 4 + j) * 128 + c];
        }
#pragma unroll
        for (int r = 0; r < RB; ++r) {
            float4 xv = *(const float4*)(&xs[r][k4 * 4]);
            acc0[r] = fmaf(xv.x, w0[0], acc0[r]);
            acc0[r] = fmaf(xv.y, w0[1], acc0[r]);
            acc0[r] = fmaf(xv.z, w0[2], acc0[r]);
            acc0[r] = fmaf(xv.w, w0[3], acc0[r]);
            acc1[r] = fmaf(xv.x, w1[0], acc1[r]);
            acc1[r] = fmaf(xv.y, w1[1], acc1[r]);
            acc1[r] = fmaf(xv.z, w1[2], acc1[r]);
            acc1[r] = fmaf(xv.w, w1[3], acc1[r]);
        }
    }

    const float bb0 = b0[c], bb1 = b1[c];
#pragma unroll
    for (int r = 0; r < RB; ++r) {
        int row = row0 + r;
        if (row < n) {
            o0[(size_t)row * 128 + c] = acc0[r] + bb0;
            o1[(size_t)row * 128 + c] = acc1[r] + bb1;
        }
    }
}

// ---------------- CSR build ----------------
__global__ void __launch_bounds__(TPB) hist_k(const int* __restrict__ dst,
                                              int* __restrict__ deg, int E)
{
    int e = blockIdx.x * TPB + threadIdx.x;
    if (e < E) atomicAdd(&deg[dst[e]], 1);
}

// inclusive scan of deg in blocks of 1024 (256 threads x 4); bsum[b] = block total
__global__ void __launch_bounds__(TPB) scan_a_k(const int* __restrict__ deg, int n,
                                                int* __restrict__ incl,
                                                int* __restrict__ bsum)
{
    __shared__ int ts[TPB];
    const int base = blockIdx.x * 1024;
    int vals[4], s = 0;
#pragma unroll
    for (int j = 0; j < 4; ++j) {
        int i = base + threadIdx.x * 4 + j;
        vals[j] = (i < n) ? deg[i] : 0;
        s += vals[j];
    }
    ts[threadIdx.x] = s;
    __syncthreads();
    for (int off = 1; off < TPB; off <<= 1) {
        int u = (threadIdx.x >= off) ? ts[threadIdx.x - off] : 0;
        __syncthreads();
        ts[threadIdx.x] += u;
        __syncthreads();
    }
    int run = ts[threadIdx.x] - s;  // exclusive prefix for this thread
#pragma unroll
    for (int j = 0; j < 4; ++j) {
        run += vals[j];
        int i = base + threadIdx.x * 4 + j;
        if (i < n) incl[i] = run;
    }
    if (threadIdx.x == TPB - 1) bsum[blockIdx.x] = ts[TPB - 1];
}

// exclusive scan of block sums in place (nb <= 256)
__global__ void __launch_bounds__(TPB) scan_b_k(int* __restrict__ bsum, int nb)
{
    __shared__ int ts[TPB];
    int t = threadIdx.x;
    int v = (t < nb) ? bsum[t] : 0;
    ts[t] = v;
    __syncthreads();
    for (int off = 1; off < TPB; off <<= 1) {
        int u = (t >= off) ? ts[t - off] : 0;
        __syncthreads();
        ts[t] += u;
        __syncthreads();
    }
    if (t < nb) bsum[t] = ts[t] - v;
}

__global__ void __launch_bounds__(TPB) finalize_k(const int* __restrict__ incl,
                                                  const int* __restrict__ deg,
                                                  const int* __restrict__ bsum, int n,
                                                  int* __restrict__ row_ptr,
                                                  int* __restrict__ cursor)
{
    const int base = blockIdx.x * 1024;
    const int boff = bsum[blockIdx.x];
#pragma unroll
    for (int j = 0; j < 4; ++j) {
        int i = base + threadIdx.x * 4 + j;
        if (i < n) {
            int iv = incl[i] + boff;
            int st = iv - deg[i];
            row_ptr[i] = st;
            cursor[i] = st;
            if (i == n - 1) row_ptr[n] = iv;
        }
    }
}

__global__ void __launch_bounds__(TPB) scatter_k(
    const int* __restrict__ src, const int* __restrict__ dst,
    const float* __restrict__ ea, int* __restrict__ cursor,
    int* __restrict__ csr_src, float* __restrict__ csr_ea, int E)
{
    int e = blockIdx.x * TPB + threadIdx.x;
    if (e >= E) return;
    int pos = atomicAdd(&cursor[dst[e]], 1);
    csr_src[pos] = src[e];
    csr_ea[pos] = ea[e];
}

// ---- fused per-node gather: online softmax over in-edges + skip + ReLU ----
// One wave (64 lanes) per node; lane owns float2 of the 128-dim state.
// comp = 2*lane -> head = lane>>4, so per-head dot reduces in 16-lane groups.
__global__ void __launch_bounds__(TPB) node_attn_k(
    const float* __restrict__ q, const float* __restrict__ k,
    const float* __restrict__ v, const float* __restrict__ skip,
    const float* __restrict__ We,
    const int* __restrict__ row_ptr, const int* __restrict__ csr_src,
    const float* __restrict__ csr_ea,
    float* __restrict__ out, int n)
{
    int node = blockIdx.x * 4 + (threadIdx.x >> 6);
    if (node >= n) return;
    int lane = threadIdx.x & 63;

    float2 qv = *(const float2*)(q + (size_t)node * 128 + lane * 2);
    float2 we = *(const float2*)(We + lane * 2);
    int p0 = row_ptr[node], p1 = row_ptr[node + 1];

    float m = -3.4e38f, l = 0.f;
    float2 acc = make_float2(0.f, 0.f);

    for (int base = p0; base < p1; base += 64) {
        int cnt = min(64, p1 - base);
        int sv = 0;
        float av = 0.f;
        if (lane < cnt) {
            sv = csr_src[base + lane];
            av = csr_ea[base + lane];
        }
        for (int j = 0; j < cnt; ++j) {
            int s = __shfl(sv, j);
            float a = __shfl(av, j);
            float2 kv = *(const float2*)(k + (size_t)s * 128 + lane * 2);
            float2 vv = *(const float2*)(v + (size_t)s * 128 + lane * 2);
            float p = fmaf(a, we.x, kv.x) * qv.x + fmaf(a, we.y, kv.y) * qv.y;
            p += __shfl_xor(p, 1);
            p += __shfl_xor(p, 2);
            p += __shfl_xor(p, 4);
            p += __shfl_xor(p, 8);
            float al = p * 0.17677669529663687f;  // / sqrt(32)
            float mn = fmax(m, al);
            float sc = __expf(m - mn);   // first iter: exp(-inf)=0
            float pe = __expf(al - mn);
            acc.x = fmaf(acc.x, sc, pe * fmaf(a, we.x, vv.x));
            acc.y = fmaf(acc.y, sc, pe * fmaf(a, we.y, vv.y));
            l = fmaf(l, sc, pe);
            m = mn;
        }
    }

    float inv = 1.f / (l + 1e-16f);
    float2 sk = *(const float2*)(skip + (size_t)node * 128 + lane * 2);
    float2 o;
    o.x = fmaxf(fmaf(acc.x, inv, sk.x), 0.f);
    o.y = fmaxf(fmaf(acc.y, inv, sk.y), 0.f);
    *(float2*)(out + (size_t)node * 128 + lane * 2) = o;
}

extern "C" void kernel_launch(void* const* d_in, const int* in_sizes, int n_in,
                              void* d_out, int out_size, void* d_ws, size_t ws_size,
                              hipStream_t stream)
{
    const float* x   = (const float*)d_in[0];
    const int*   ei  = (const int*)d_in[1];
    const float* ea  = (const float*)d_in[2];
    const float* Wq1 = (const float*)d_in[3];  const float* bq1 = (const float*)d_in[4];
    const float* Wk1 = (const float*)d_in[5];  const float* bk1 = (const float*)d_in[6];
    const float* Wv1 = (const float*)d_in[7];  const float* bv1 = (const float*)d_in[8];
    const float* We1 = (const float*)d_in[9];
    const float* Ws1 = (const float*)d_in[10]; const float* bs1 = (const float*)d_in[11];
    const float* Wq2 = (const float*)d_in[12]; const float* bq2 = (const float*)d_in[13];
    const float* Wk2 = (const float*)d_in[14]; const float* bk2 = (const float*)d_in[15];
    const float* Wv2 = (const float*)d_in[16]; const float* bv2 = (const float*)d_in[17];
    const float* We2 = (const float*)d_in[18];
    const float* Ws2 = (const float*)d_in[19]; const float* bs2 = (const float*)d_in[20];

    const int N = in_sizes[0] / 128;
    const int E = in_sizes[1] / 2;
    const int* src = ei;
    const int* dst = ei + E;
    float* outf = (float*)d_out;

    // workspace layout
    float* q = (float*)d_ws;
    float* k = q + (size_t)N * 128;
    float* v = k + (size_t)N * 128;
    float* h = v + (size_t)N * 128;              // layer1 skip+out (in-place)
    int*   row_ptr = (int*)(h + (size_t)N * 128); // N+1
    int*   deg     = row_ptr + (N + 1);
    int*   incl    = deg + N;
    int*   cursor  = incl + N;
    int*   bsum    = cursor + N;                  // 256
    int*   csr_src = bsum + 256;                  // E
    float* csr_ea  = (float*)(csr_src + E);       // E

    const int gE   = (E + TPB - 1) / TPB;
    const int nb   = (N + 1023) / 1024;
    const int gN16 = (N + 15) / 16;
    const int gN4  = (N + 3) / 4;

    // ---- CSR build (once, shared by both layers) ----
    hipMemsetAsync(deg, 0, (size_t)N * sizeof(int), stream);
    hist_k<<<gE, TPB, 0, stream>>>(dst, deg, E);
    scan_a_k<<<nb, TPB, 0, stream>>>(deg, N, incl, bsum);
    scan_b_k<<<1, TPB, 0, stream>>>(bsum, nb);
    finalize_k<<<nb, TPB, 0, stream>>>(incl, deg, bsum, N, row_ptr, cursor);
    scatter_k<<<gE, TPB, 0, stream>>>(src, dst, ea, cursor, csr_src, csr_ea, E);

    // ---- layer 1 ----
    gemm_qkvs_k<16><<<gN16, TPB, 0, stream>>>(x, N, Wq1, bq1, Wk1, bk1, Wv1, bv1,
                                              Ws1, bs1, q, k, v, h);
    node_attn_k<<<gN4, TPB, 0, stream>>>(q, k, v, h, We1, row_ptr, csr_src, csr_ea,
                                         h, N);

    // ---- layer 2 ----
    gemm_qkvs_k<16><<<gN16, TPB, 0, stream>>>(h, N, Wq2, bq2, Wk2, bk2, Wv2, bv2,
                                              Ws2, bs2, q, k, v, outf);
    node_attn_k<<<gN4, TPB, 0, stream>>>(q, k, v, outf, We2, row_ptr, csr_src, csr_ea,
                                         outf, N);
}

// Round 3
// 435.683 us; speedup vs baseline: 7.4567x; 1.2949x over previous
//
#include <hip/hip_runtime.h>

// TransformerConv x2 on MI355X — MFMA GEMM + gather attention.
// N=50000, E=800000, H=4, C=32, D=128.

#define TPB 256

typedef __attribute__((ext_vector_type(8))) short short8v;
typedef __attribute__((ext_vector_type(4))) float f32x4;

__device__ __forceinline__ unsigned short f2bf(float f) {
    unsigned u = __float_as_uint(f);
    u = (u + 0x7FFFu + ((u >> 16) & 1u)) >> 16;
    return (unsigned short)u;
}

// ---- fp32 -> bf16 convert (vectorized) ----
__global__ void __launch_bounds__(TPB) cvt_bf16_k(const float* __restrict__ in,
                                                  unsigned short* __restrict__ out,
                                                  int n4)
{
    int i = blockIdx.x * TPB + threadIdx.x;
    if (i >= n4) return;
    float4 v = *(const float4*)(in + (size_t)i * 4);
    ushort4 o;
    o.x = f2bf(v.x); o.y = f2bf(v.y); o.z = f2bf(v.z); o.w = f2bf(v.w);
    *(ushort4*)(out + (size_t)i * 4) = o;
}

// ---- pack weights into MFMA B-fragment layout ----
// pack[(((g*8+c)*4+t)*64+l)*8+j] = Wg[k=t*32+(l>>4)*8+j][n=c*16+(l&15)]
__global__ void __launch_bounds__(TPB) prepack_k(
    const float* __restrict__ Wq, const float* __restrict__ Wk,
    const float* __restrict__ Wv, const float* __restrict__ Ws,
    unsigned short* __restrict__ pack)
{
    int i = blockIdx.x * TPB + threadIdx.x;   // 65536 total
    int j = i & 7, l = (i >> 3) & 63, t = (i >> 9) & 3, c = (i >> 11) & 7, g = (i >> 14) & 3;
    const float* W = g == 0 ? Wq : (g == 1 ? Wk : (g == 2 ? Wv : Ws));
    int kk = t * 32 + (l >> 4) * 8 + j;
    int nn = c * 16 + (l & 15);
    pack[i] = f2bf(W[kk * 128 + nn]);
}

// ---- MFMA GEMM: out[g] = A(bf16) @ Wg + bg, g in {q,k,v,s} via blockIdx.y ----
// Block: 256 threads = 4 waves; wave computes 32 rows x 128 cols; K=128 in regs.
__global__ void __launch_bounds__(TPB) gemm_mfma_k(
    const unsigned short* __restrict__ A, int M,
    const unsigned short* __restrict__ pack,
    const float* __restrict__ bq, const float* __restrict__ bk,
    const float* __restrict__ bv, const float* __restrict__ bs,
    float* __restrict__ oq, float* __restrict__ ok,
    float* __restrict__ ov, float* __restrict__ os)
{
    const int g = blockIdx.y;
    const int row0 = blockIdx.x * 128;
    const int wv = threadIdx.x >> 6;
    const int lane = threadIdx.x & 63;
    const int rbase = row0 + wv * 32;
    const int rlo = lane & 15;
    const int kg = (lane >> 4) * 8;

    const short8v z8 = {0, 0, 0, 0, 0, 0, 0, 0};
    short8v a[2][4];
#pragma unroll
    for (int m = 0; m < 2; ++m) {
        int row = rbase + m * 16 + rlo;
#pragma unroll
        for (int t = 0; t < 4; ++t)
            a[m][t] = (row < M) ? *(const short8v*)(A + (size_t)row * 128 + t * 32 + kg)
                                : z8;
    }

    f32x4 acc[2][8];
#pragma unroll
    for (int m = 0; m < 2; ++m)
#pragma unroll
        for (int c = 0; c < 8; ++c)
            acc[m][c] = (f32x4){0.f, 0.f, 0.f, 0.f};

    const unsigned short* bp = pack + (size_t)g * (8 * 4 * 512);
#pragma unroll
    for (int c = 0; c < 8; ++c) {
        short8v b[4];
#pragma unroll
        for (int t = 0; t < 4; ++t)
            b[t] = *(const short8v*)(bp + (c * 4 + t) * 512 + lane * 8);
#pragma unroll
        for (int t = 0; t < 4; ++t) {
            acc[0][c] = __builtin_amdgcn_mfma_f32_16x16x32_bf16(a[0][t], b[t], acc[0][c], 0, 0, 0);
            acc[1][c] = __builtin_amdgcn_mfma_f32_16x16x32_bf16(a[1][t], b[t], acc[1][c], 0, 0, 0);
        }
    }

    const float* bias = g == 0 ? bq : (g == 1 ? bk : (g == 2 ? bv : bs));
    float* out = g == 0 ? oq : (g == 1 ? ok : (g == 2 ? ov : os));
    const int rof = (lane >> 4) * 4;
#pragma unroll
    for (int c = 0; c < 8; ++c) {
        float bb = bias[c * 16 + rlo];
#pragma unroll
        for (int m = 0; m < 2; ++m) {
#pragma unroll
            for (int j = 0; j < 4; ++j) {
                int row = rbase + m * 16 + rof + j;
                if (row < M) out[(size_t)row * 128 + c * 16 + rlo] = acc[m][c][j] + bb;
            }
        }
    }
}

// ---------------- CSR build ----------------
__global__ void __launch_bounds__(TPB) hist_k(const int* __restrict__ dst,
                                              int* __restrict__ deg, int E)
{
    int e = blockIdx.x * TPB + threadIdx.x;
    if (e < E) atomicAdd(&deg[dst[e]], 1);
}

__global__ void __launch_bounds__(TPB) scan_a_k(const int* __restrict__ deg, int n,
                                                int* __restrict__ incl,
                                                int* __restrict__ bsum)
{
    __shared__ int ts[TPB];
    const int base = blockIdx.x * 1024;
    int vals[4], s = 0;
#pragma unroll
    for (int j = 0; j < 4; ++j) {
        int i = base + threadIdx.x * 4 + j;
        vals[j] = (i < n) ? deg[i] : 0;
        s += vals[j];
    }
    ts[threadIdx.x] = s;
    __syncthreads();
    for (int off = 1; off < TPB; off <<= 1) {
        int u = (threadIdx.x >= off) ? ts[threadIdx.x - off] : 0;
        __syncthreads();
        ts[threadIdx.x] += u;
        __syncthreads();
    }
    int run = ts[threadIdx.x] - s;
#pragma unroll
    for (int j = 0; j < 4; ++j) {
        run += vals[j];
        int i = base + threadIdx.x * 4 + j;
        if (i < n) incl[i] = run;
    }
    if (threadIdx.x == TPB - 1) bsum[blockIdx.x] = ts[TPB - 1];
}

__global__ void __launch_bounds__(TPB) scan_b_k(int* __restrict__ bsum, int nb)
{
    __shared__ int ts[TPB];
    int t = threadIdx.x;
    int v = (t < nb) ? bsum[t] : 0;
    ts[t] = v;
    __syncthreads();
    for (int off = 1; off < TPB; off <<= 1) {
        int u = (t >= off) ? ts[t - off] : 0;
        __syncthreads();
        ts[t] += u;
        __syncthreads();
    }
    if (t < nb) bsum[t] = ts[t] - v;
}

__global__ void __launch_bounds__(TPB) finalize_k(const int* __restrict__ incl,
                                                  const int* __restrict__ deg,
                                                  const int* __restrict__ bsum, int n,
                                                  int* __restrict__ row_ptr,
                                                  int* __restrict__ cursor)
{
    const int base = blockIdx.x * 1024;
    const int boff = bsum[blockIdx.x];
#pragma unroll
    for (int j = 0; j < 4; ++j) {
        int i = base + threadIdx.x * 4 + j;
        if (i < n) {
            int iv = incl[i] + boff;
            int st = iv - deg[i];
            row_ptr[i] = st;
            cursor[i] = st;
            if (i == n - 1) row_ptr[n] = iv;
        }
    }
}

__global__ void __launch_bounds__(TPB) scatter_k(
    const int* __restrict__ src, const int* __restrict__ dst,
    const float* __restrict__ ea, int* __restrict__ cursor,
    int* __restrict__ csr_src, float* __restrict__ csr_ea, int E)
{
    int e = blockIdx.x * TPB + threadIdx.x;
    if (e >= E) return;
    int pos = atomicAdd(&cursor[dst[e]], 1);
    csr_src[pos] = src[e];
    csr_ea[pos] = ea[e];
}

// ---- fused per-node gather: online softmax over in-edges + skip + ReLU ----
template <bool BF16OUT>
__global__ void __launch_bounds__(TPB) node_attn_k(
    const float* __restrict__ q, const float* __restrict__ k,
    const float* __restrict__ v, const float* __restrict__ skip,
    const float* __restrict__ We,
    const int* __restrict__ row_ptr, const int* __restrict__ csr_src,
    const float* __restrict__ csr_ea,
    void* __restrict__ outp, int n)
{
    int node = blockIdx.x * 4 + (threadIdx.x >> 6);
    if (node >= n) return;
    int lane = threadIdx.x & 63;

    float2 qv = *(const float2*)(q + (size_t)node * 128 + lane * 2);
    float2 we = *(const float2*)(We + lane * 2);
    int p0 = row_ptr[node], p1 = row_ptr[node + 1];

    float m = -3.4e38f, l = 0.f;
    float2 acc = make_float2(0.f, 0.f);

    for (int base = p0; base < p1; base += 64) {
        int cnt = min(64, p1 - base);
        int sv = 0;
        float av = 0.f;
        if (lane < cnt) {
            sv = csr_src[base + lane];
            av = csr_ea[base + lane];
        }
        for (int j = 0; j < cnt; ++j) {
            int s = __shfl(sv, j);
            float a = __shfl(av, j);
            float2 kv = *(const float2*)(k + (size_t)s * 128 + lane * 2);
            float2 vv = *(const float2*)(v + (size_t)s * 128 + lane * 2);
            float p = fmaf(a, we.x, kv.x) * qv.x + fmaf(a, we.y, kv.y) * qv.y;
            p += __shfl_xor(p, 1);
            p += __shfl_xor(p, 2);
            p += __shfl_xor(p, 4);
            p += __shfl_xor(p, 8);
            float al = p * 0.17677669529663687f;  // / sqrt(32)
            float mn = fmax(m, al);
            float sc = __expf(m - mn);
            float pe = __expf(al - mn);
            acc.x = fmaf(acc.x, sc, pe * fmaf(a, we.x, vv.x));
            acc.y = fmaf(acc.y, sc, pe * fmaf(a, we.y, vv.y));
            l = fmaf(l, sc, pe);
            m = mn;
        }
    }

    float inv = 1.f / (l + 1e-16f);
    float2 sk = *(const float2*)(skip + (size_t)node * 128 + lane * 2);
    float ox = fmaxf(fmaf(acc.x, inv, sk.x), 0.f);
    float oy = fmaxf(fmaf(acc.y, inv, sk.y), 0.f);
    if (BF16OUT) {
        ushort2 o2;
        o2.x = f2bf(ox); o2.y = f2bf(oy);
        *(ushort2*)((unsigned short*)outp + (size_t)node * 128 + lane * 2) = o2;
    } else {
        *(float2*)((float*)outp + (size_t)node * 128 + lane * 2) = make_float2(ox, oy);
    }
}

extern "C" void kernel_launch(void* const* d_in, const int* in_sizes, int n_in,
                              void* d_out, int out_size, void* d_ws, size_t ws_size,
                              hipStream_t stream)
{
    const float* x   = (const float*)d_in[0];
    const int*   ei  = (const int*)d_in[1];
    const float* ea  = (const float*)d_in[2];
    const float* Wq1 = (const float*)d_in[3];  const float* bq1 = (const float*)d_in[4];
    const float* Wk1 = (const float*)d_in[5];  const float* bk1 = (const float*)d_in[6];
    const float* Wv1 = (const float*)d_in[7];  const float* bv1 = (const float*)d_in[8];
    const float* We1 = (const float*)d_in[9];
    const float* Ws1 = (const float*)d_in[10]; const float* bs1 = (const float*)d_in[11];
    const float* Wq2 = (const float*)d_in[12]; const float* bq2 = (const float*)d_in[13];
    const float* Wk2 = (const float*)d_in[14]; const float* bk2 = (const float*)d_in[15];
    const float* Wv2 = (const float*)d_in[16]; const float* bv2 = (const float*)d_in[17];
    const float* We2 = (const float*)d_in[18];
    const float* Ws2 = (const float*)d_in[19]; const float* bs2 = (const float*)d_in[20];

    const int N = in_sizes[0] / 128;
    const int E = in_sizes[1] / 2;
    const int* src = ei;
    const int* dst = ei + E;
    float* outf = (float*)d_out;

    // workspace layout
    float* q = (float*)d_ws;
    float* k = q + (size_t)N * 128;
    float* v = k + (size_t)N * 128;
    float* s = v + (size_t)N * 128;                 // skip buffer
    unsigned short* xb   = (unsigned short*)(s + (size_t)N * 128); // bf16 in (x, then h)
    unsigned short* pk1  = xb + (size_t)N * 128;    // 65536
    unsigned short* pk2  = pk1 + 65536;
    int*   row_ptr = (int*)(pk2 + 65536);           // N+1
    int*   deg     = row_ptr + (N + 1);
    int*   incl    = deg + N;
    int*   cursor  = incl + N;
    int*   bsum    = cursor + N;                    // 256
    int*   csr_src = bsum + 256;                    // E
    float* csr_ea  = (float*)(csr_src + E);         // E

    const int gE   = (E + TPB - 1) / TPB;
    const int nb   = (N + 1023) / 1024;
    const int gN4  = (N + 3) / 4;
    const int gCv  = (N * 128 / 4 + TPB - 1) / TPB;
    const dim3 gG((N + 127) / 128, 4);

    // ---- CSR build (shared by both layers) ----
    hipMemsetAsync(deg, 0, (size_t)N * sizeof(int), stream);
    hist_k<<<gE, TPB, 0, stream>>>(dst, deg, E);
    scan_a_k<<<nb, TPB, 0, stream>>>(deg, N, incl, bsum);
    scan_b_k<<<1, TPB, 0, stream>>>(bsum, nb);
    finalize_k<<<nb, TPB, 0, stream>>>(incl, deg, bsum, N, row_ptr, cursor);
    scatter_k<<<gE, TPB, 0, stream>>>(src, dst, ea, cursor, csr_src, csr_ea, E);

    // ---- packs + input convert ----
    prepack_k<<<65536 / TPB, TPB, 0, stream>>>(Wq1, Wk1, Wv1, Ws1, pk1);
    prepack_k<<<65536 / TPB, TPB, 0, stream>>>(Wq2, Wk2, Wv2, Ws2, pk2);
    cvt_bf16_k<<<gCv, TPB, 0, stream>>>(x, xb, N * 128 / 4);

    // ---- layer 1 ----
    gemm_mfma_k<<<gG, TPB, 0, stream>>>(xb, N, pk1, bq1, bk1, bv1, bs1, q, k, v, s);
    node_attn_k<true><<<gN4, TPB, 0, stream>>>(q, k, v, s, We1, row_ptr, csr_src,
                                               csr_ea, xb, N);  // h -> bf16 (reuse xb)
    // ---- layer 2 ----
    gemm_mfma_k<<<gG, TPB, 0, stream>>>(xb, N, pk2, bq2, bk2, bv2, bs2, q, k, v, s);
    node_attn_k<false><<<gN4, TPB, 0, stream>>>(q, k, v, s, We2, row_ptr, csr_src,
                                                csr_ea, outf, N);
}

// Round 4
// 326.446 us; speedup vs baseline: 9.9519x; 1.3346x over previous
//
#include <hip/hip_runtime.h>

// TransformerConv x2 on MI355X — MFMA GEMM (bf16 out) + bf16 gather attention.
// N=50000, E=800000, H=4, C=32, D=128.

#define TPB 256

typedef __attribute__((ext_vector_type(8))) short short8v;
typedef __attribute__((ext_vector_type(4))) float f32x4;

__device__ __forceinline__ unsigned short f2bf(float f) {
    unsigned u = __float_as_uint(f);
    u = (u + 0x7FFFu + ((u >> 16) & 1u)) >> 16;
    return (unsigned short)u;
}
__device__ __forceinline__ float bf2f(unsigned short s) {
    return __uint_as_float((unsigned)s << 16);
}
__device__ __forceinline__ float4 bf4_to_f4(ushort4 u) {
    return make_float4(bf2f(u.x), bf2f(u.y), bf2f(u.z), bf2f(u.w));
}

// ---- fp32 -> bf16 convert (vectorized) ----
__global__ void __launch_bounds__(TPB) cvt_bf16_k(const float* __restrict__ in,
                                                  unsigned short* __restrict__ out,
                                                  int n4)
{
    int i = blockIdx.x * TPB + threadIdx.x;
    if (i >= n4) return;
    float4 v = *(const float4*)(in + (size_t)i * 4);
    ushort4 o;
    o.x = f2bf(v.x); o.y = f2bf(v.y); o.z = f2bf(v.z); o.w = f2bf(v.w);
    *(ushort4*)(out + (size_t)i * 4) = o;
}

// ---- pack weights into MFMA B-fragment layout ----
__global__ void __launch_bounds__(TPB) prepack_k(
    const float* __restrict__ Wq, const float* __restrict__ Wk,
    const float* __restrict__ Wv, const float* __restrict__ Ws,
    unsigned short* __restrict__ pack)
{
    int i = blockIdx.x * TPB + threadIdx.x;   // 65536 total
    int j = i & 7, l = (i >> 3) & 63, t = (i >> 9) & 3, c = (i >> 11) & 7, g = (i >> 14) & 3;
    const float* W = g == 0 ? Wq : (g == 1 ? Wk : (g == 2 ? Wv : Ws));
    int kk = t * 32 + (l >> 4) * 8 + j;
    int nn = c * 16 + (l & 15);
    pack[i] = f2bf(W[kk * 128 + nn]);
}

// ---- MFMA GEMM: g in {q,k,v} -> bf16 out, g==3 (skip) -> fp32 out ----
__global__ void __launch_bounds__(TPB) gemm_mfma_k(
    const unsigned short* __restrict__ A, int M,
    const unsigned short* __restrict__ pack,
    const float* __restrict__ bq, const float* __restrict__ bk,
    const float* __restrict__ bv, const float* __restrict__ bs,
    unsigned short* __restrict__ oq, unsigned short* __restrict__ ok,
    unsigned short* __restrict__ ov, float* __restrict__ os)
{
    const int g = blockIdx.y;
    const int row0 = blockIdx.x * 128;
    const int wv = threadIdx.x >> 6;
    const int lane = threadIdx.x & 63;
    const int rbase = row0 + wv * 32;
    const int rlo = lane & 15;
    const int kg = (lane >> 4) * 8;

    const short8v z8 = {0, 0, 0, 0, 0, 0, 0, 0};
    short8v a[2][4];
#pragma unroll
    for (int m = 0; m < 2; ++m) {
        int row = rbase + m * 16 + rlo;
#pragma unroll
        for (int t = 0; t < 4; ++t)
            a[m][t] = (row < M) ? *(const short8v*)(A + (size_t)row * 128 + t * 32 + kg)
                                : z8;
    }

    f32x4 acc[2][8];
#pragma unroll
    for (int m = 0; m < 2; ++m)
#pragma unroll
        for (int c = 0; c < 8; ++c)
            acc[m][c] = (f32x4){0.f, 0.f, 0.f, 0.f};

    const unsigned short* bp = pack + (size_t)g * (8 * 4 * 512);
#pragma unroll
    for (int c = 0; c < 8; ++c) {
        short8v b[4];
#pragma unroll
        for (int t = 0; t < 4; ++t)
            b[t] = *(const short8v*)(bp + (c * 4 + t) * 512 + lane * 8);
#pragma unroll
        for (int t = 0; t < 4; ++t) {
            acc[0][c] = __builtin_amdgcn_mfma_f32_16x16x32_bf16(a[0][t], b[t], acc[0][c], 0, 0, 0);
            acc[1][c] = __builtin_amdgcn_mfma_f32_16x16x32_bf16(a[1][t], b[t], acc[1][c], 0, 0, 0);
        }
    }

    const float* bias = g == 0 ? bq : (g == 1 ? bk : (g == 2 ? bv : bs));
    const int rof = (lane >> 4) * 4;
    if (g == 3) {
#pragma unroll
        for (int c = 0; c < 8; ++c) {
            float bb = bias[c * 16 + rlo];
#pragma unroll
            for (int m = 0; m < 2; ++m)
#pragma unroll
                for (int j = 0; j < 4; ++j) {
                    int row = rbase + m * 16 + rof + j;
                    if (row < M) os[(size_t)row * 128 + c * 16 + rlo] = acc[m][c][j] + bb;
                }
        }
    } else {
        unsigned short* out = g == 0 ? oq : (g == 1 ? ok : ov);
#pragma unroll
        for (int c = 0; c < 8; ++c) {
            float bb = bias[c * 16 + rlo];
#pragma unroll
            for (int m = 0; m < 2; ++m)
#pragma unroll
                for (int j = 0; j < 4; ++j) {
                    int row = rbase + m * 16 + rof + j;
                    if (row < M) out[(size_t)row * 128 + c * 16 + rlo] = f2bf(acc[m][c][j] + bb);
                }
        }
    }
}

// ---------------- CSR build ----------------
__global__ void __launch_bounds__(TPB) hist_k(const int* __restrict__ dst,
                                              int* __restrict__ deg, int E)
{
    int e = blockIdx.x * TPB + threadIdx.x;
    if (e < E) atomicAdd(&deg[dst[e]], 1);
}

__global__ void __launch_bounds__(TPB) scan_a_k(const int* __restrict__ deg, int n,
                                                int* __restrict__ incl,
                                                int* __restrict__ bsum)
{
    __shared__ int ts[TPB];
    const int base = blockIdx.x * 1024;
    int vals[4], s = 0;
#pragma unroll
    for (int j = 0; j < 4; ++j) {
        int i = base + threadIdx.x * 4 + j;
        vals[j] = (i < n) ? deg[i] : 0;
        s += vals[j];
    }
    ts[threadIdx.x] = s;
    __syncthreads();
    for (int off = 1; off < TPB; off <<= 1) {
        int u = (threadIdx.x >= off) ? ts[threadIdx.x - off] : 0;
        __syncthreads();
        ts[threadIdx.x] += u;
        __syncthreads();
    }
    int run = ts[threadIdx.x] - s;
#pragma unroll
    for (int j = 0; j < 4; ++j) {
        run += vals[j];
        int i = base + threadIdx.x * 4 + j;
        if (i < n) incl[i] = run;
    }
    if (threadIdx.x == TPB - 1) bsum[blockIdx.x] = ts[TPB - 1];
}

__global__ void __launch_bounds__(TPB) scan_b_k(int* __restrict__ bsum, int nb)
{
    __shared__ int ts[TPB];
    int t = threadIdx.x;
    int v = (t < nb) ? bsum[t] : 0;
    ts[t] = v;
    __syncthreads();
    for (int off = 1; off < TPB; off <<= 1) {
        int u = (t >= off) ? ts[t - off] : 0;
        __syncthreads();
        ts[t] += u;
        __syncthreads();
    }
    if (t < nb) bsum[t] = ts[t] - v;
}

__global__ void __launch_bounds__(TPB) finalize_k(const int* __restrict__ incl,
                                                  const int* __restrict__ deg,
                                                  const int* __restrict__ bsum, int n,
                                                  int* __restrict__ row_ptr,
                                                  int* __restrict__ cursor)
{
    const int base = blockIdx.x * 1024;
    const int boff = bsum[blockIdx.x];
#pragma unroll
    for (int j = 0; j < 4; ++j) {
        int i = base + threadIdx.x * 4 + j;
        if (i < n) {
            int iv = incl[i] + boff;
            int st = iv - deg[i];
            row_ptr[i] = st;
            cursor[i] = st;
            if (i == n - 1) row_ptr[n] = iv;
        }
    }
}

__global__ void __launch_bounds__(TPB) scatter_k(
    const int* __restrict__ src, const int* __restrict__ dst,
    const float* __restrict__ ea, int* __restrict__ cursor,
    int* __restrict__ csr_src, float* __restrict__ csr_ea, int E)
{
    int e = blockIdx.x * TPB + threadIdx.x;
    if (e >= E) return;
    int pos = atomicAdd(&cursor[dst[e]], 1);
    csr_src[pos] = src[e];
    csr_ea[pos] = ea[e];
}

// ---- fused per-node gather attention (bf16 q/k/v) ----
// Wave per node. Lanes 0..31 own k-comps 4*lane..+3; lanes 32..63 own v-comps.
// One 8-B gather per edge covers k AND v. Head h reduce = 8-lane xor shuffle.
template <bool BF16OUT>
__global__ void __launch_bounds__(TPB) node_attn_k(
    const unsigned short* __restrict__ q, const unsigned short* __restrict__ k,
    const unsigned short* __restrict__ v, const float* __restrict__ skip,
    const float* __restrict__ We,
    const int* __restrict__ row_ptr, const int* __restrict__ csr_src,
    const float* __restrict__ csr_ea,
    void* __restrict__ outp, int n)
{
    const int node = blockIdx.x * 4 + (threadIdx.x >> 6);
    if (node >= n) return;
    const int lane = threadIdx.x & 63;
    const bool vside = lane >= 32;
    const int c4 = (lane & 31) * 4;
    const unsigned short* gbase = vside ? v : k;

    const float4 we4 = *(const float4*)(We + c4);
    const float4 qv = bf4_to_f4(*(const ushort4*)(q + (size_t)node * 128 + c4));
    const int p0 = row_ptr[node], p1 = row_ptr[node + 1];
    const float C = 0.17677669529663687f; // 1/sqrt(32)

    float m = -3.4e38f, l = 0.f;
    float4 acc = make_float4(0.f, 0.f, 0.f, 0.f);

    for (int base = p0; base < p1; base += 64) {
        const int cnt = min(64, p1 - base);
        int sv = 0;
        float av = 0.f;
        if (lane < cnt) {
            sv = csr_src[base + lane];
            av = csr_ea[base + lane];
        }
        int j = 0;
        for (; j + 4 <= cnt; j += 4) {
            int s0 = __shfl(sv, j), s1 = __shfl(sv, j + 1);
            int s2 = __shfl(sv, j + 2), s3 = __shfl(sv, j + 3);
            float a0 = __shfl(av, j), a1 = __shfl(av, j + 1);
            float a2 = __shfl(av, j + 2), a3 = __shfl(av, j + 3);
            ushort4 u0 = *(const ushort4*)(gbase + (size_t)s0 * 128 + c4);
            ushort4 u1 = *(const ushort4*)(gbase + (size_t)s1 * 128 + c4);
            ushort4 u2 = *(const ushort4*)(gbase + (size_t)s2 * 128 + c4);
            ushort4 u3 = *(const ushort4*)(gbase + (size_t)s3 * 128 + c4);
            float4 f0 = bf4_to_f4(u0), f1 = bf4_to_f4(u1);
            float4 f2 = bf4_to_f4(u2), f3 = bf4_to_f4(u3);
            float4 e0, e1, e2, e3;
            e0.x = fmaf(a0, we4.x, f0.x); e0.y = fmaf(a0, we4.y, f0.y);
            e0.z = fmaf(a0, we4.z, f0.z); e0.w = fmaf(a0, we4.w, f0.w);
            e1.x = fmaf(a1, we4.x, f1.x); e1.y = fmaf(a1, we4.y, f1.y);
            e1.z = fmaf(a1, we4.z, f1.z); e1.w = fmaf(a1, we4.w, f1.w);
            e2.x = fmaf(a2, we4.x, f2.x); e2.y = fmaf(a2, we4.y, f2.y);
            e2.z = fmaf(a2, we4.z, f2.z); e2.w = fmaf(a2, we4.w, f2.w);
            e3.x = fmaf(a3, we4.x, f3.x); e3.y = fmaf(a3, we4.y, f3.y);
            e3.z = fmaf(a3, we4.z, f3.z); e3.w = fmaf(a3, we4.w, f3.w);
            float d0 = e0.x * qv.x + e0.y * qv.y + e0.z * qv.z + e0.w * qv.w;
            float d1 = e1.x * qv.x + e1.y * qv.y + e1.z * qv.z + e1.w * qv.w;
            float d2 = e2.x * qv.x + e2.y * qv.y + e2.z * qv.z + e2.w * qv.w;
            float d3 = e3.x * qv.x + e3.y * qv.y + e3.z * qv.z + e3.w * qv.w;
            d0 += __shfl_xor(d0, 1); d0 += __shfl_xor(d0, 2); d0 += __shfl_xor(d0, 4);
            d1 += __shfl_xor(d1, 1); d1 += __shfl_xor(d1, 2); d1 += __shfl_xor(d1, 4);
            d2 += __shfl_xor(d2, 1); d2 += __shfl_xor(d2, 2); d2 += __shfl_xor(d2, 4);
            d3 += __shfl_xor(d3, 1); d3 += __shfl_xor(d3, 2); d3 += __shfl_xor(d3, 4);
            float al0 = __shfl(d0, lane & 31) * C;
            float al1 = __shfl(d1, lane & 31) * C;
            float al2 = __shfl(d2, lane & 31) * C;
            float al3 = __shfl(d3, lane & 31) * C;
            float mn = fmax(m, fmax(fmax(al0, al1), fmax(al2, al3)));
            float sc = __expf(m - mn);
            float pe0 = __expf(al0 - mn), pe1 = __expf(al1 - mn);
            float pe2 = __expf(al2 - mn), pe3 = __expf(al3 - mn);
            l = fmaf(l, sc, (pe0 + pe1) + (pe2 + pe3));
            acc.x = fmaf(acc.x, sc, fmaf(pe0, e0.x, fmaf(pe1, e1.x, fmaf(pe2, e2.x, pe3 * e3.x))));
            acc.y = fmaf(acc.y, sc, fmaf(pe0, e0.y, fmaf(pe1, e1.y, fmaf(pe2, e2.y, pe3 * e3.y))));
            acc.z = fmaf(acc.z, sc, fmaf(pe0, e0.z, fmaf(pe1, e1.z, fmaf(pe2, e2.z, pe3 * e3.z))));
            acc.w = fmaf(acc.w, sc, fmaf(pe0, e0.w, fmaf(pe1, e1.w, fmaf(pe2, e2.w, pe3 * e3.w))));
            m = mn;
        }
        for (; j < cnt; ++j) {
            int s0 = __shfl(sv, j);
            float a0 = __shfl(av, j);
            ushort4 u0 = *(const ushort4*)(gbase + (size_t)s0 * 128 + c4);
            float4 f0 = bf4_to_f4(u0);
            float4 e0;
            e0.x = fmaf(a0, we4.x, f0.x); e0.y = fmaf(a0, we4.y, f0.y);
            e0.z = fmaf(a0, we4.z, f0.z); e0.w = fmaf(a0, we4.w, f0.w);
            float d0 = e0.x * qv.x + e0.y * qv.y + e0.z * qv.z + e0.w * qv.w;
            d0 += __shfl_xor(d0, 1); d0 += __shfl_xor(d0, 2); d0 += __shfl_xor(d0, 4);
            float al0 = __shfl(d0, lane & 31) * C;
            float mn = fmax(m, al0);
            float sc = __expf(m - mn);
            float pe0 = __expf(al0 - mn);
            l = fmaf(l, sc, pe0);
            acc.x = fmaf(acc.x, sc, pe0 * e0.x);
            acc.y = fmaf(acc.y, sc, pe0 * e0.y);
            acc.z = fmaf(acc.z, sc, pe0 * e0.z);
            acc.w = fmaf(acc.w, sc, pe0 * e0.w);
            m = mn;
        }
    }

    if (vside) {
        float inv = 1.f / (l + 1e-16f);
        float4 sk = *(const float4*)(skip + (size_t)node * 128 + c4);
        float o0 = fmaxf(fmaf(acc.x, inv, sk.x), 0.f);
        float o1 = fmaxf(fmaf(acc.y, inv, sk.y), 0.f);
        float o2 = fmaxf(fmaf(acc.z, inv, sk.z), 0.f);
        float o3 = fmaxf(fmaf(acc.w, inv, sk.w), 0.f);
        if (BF16OUT) {
            ushort4 o;
            o.x = f2bf(o0); o.y = f2bf(o1); o.z = f2bf(o2); o.w = f2bf(o3);
            *(ushort4*)((unsigned short*)outp + (size_t)node * 128 + c4) = o;
        } else {
            *(float4*)((float*)outp + (size_t)node * 128 + c4) =
                make_float4(o0, o1, o2, o3);
        }
    }
}

extern "C" void kernel_launch(void* const* d_in, const int* in_sizes, int n_in,
                              void* d_out, int out_size, void* d_ws, size_t ws_size,
                              hipStream_t stream)
{
    const float* x   = (const float*)d_in[0];
    const int*   ei  = (const int*)d_in[1];
    const float* ea  = (const float*)d_in[2];
    const float* Wq1 = (const float*)d_in[3];  const float* bq1 = (const float*)d_in[4];
    const float* Wk1 = (const float*)d_in[5];  const float* bk1 = (const float*)d_in[6];
    const float* Wv1 = (const float*)d_in[7];  const float* bv1 = (const float*)d_in[8];
    const float* We1 = (const float*)d_in[9];
    const float* Ws1 = (const float*)d_in[10]; const float* bs1 = (const float*)d_in[11];
    const float* Wq2 = (const float*)d_in[12]; const float* bq2 = (const float*)d_in[13];
    const float* Wk2 = (const float*)d_in[14]; const float* bk2 = (const float*)d_in[15];
    const float* Wv2 = (const float*)d_in[16]; const float* bv2 = (const float*)d_in[17];
    const float* We2 = (const float*)d_in[18];
    const float* Ws2 = (const float*)d_in[19]; const float* bs2 = (const float*)d_in[20];

    const int N = in_sizes[0] / 128;
    const int E = in_sizes[1] / 2;
    const int* src = ei;
    const int* dst = ei + E;
    float* outf = (float*)d_out;

    // workspace layout
    unsigned short* q  = (unsigned short*)d_ws;          // N*128 bf16
    unsigned short* k  = q + (size_t)N * 128;
    unsigned short* v  = k + (size_t)N * 128;
    float*          s  = (float*)(v + (size_t)N * 128);  // N*128 f32 skip
    unsigned short* xb = (unsigned short*)(s + (size_t)N * 128); // bf16 x / h
    unsigned short* pk1 = xb + (size_t)N * 128;          // 65536
    unsigned short* pk2 = pk1 + 65536;
    int*   row_ptr = (int*)(pk2 + 65536);                // N+1
    int*   deg     = row_ptr + (N + 1);
    int*   incl    = deg + N;
    int*   cursor  = incl + N;
    int*   bsum    = cursor + N;                         // 256
    int*   csr_src = bsum + 256;                         // E
    float* csr_ea  = (float*)(csr_src + E);              // E

    const int gE   = (E + TPB - 1) / TPB;
    const int nb   = (N + 1023) / 1024;
    const int gN4  = (N + 3) / 4;
    const int gCv  = (N * 128 / 4 + TPB - 1) / TPB;
    const dim3 gG((N + 127) / 128, 4);

    // ---- CSR build (shared by both layers) ----
    hipMemsetAsync(deg, 0, (size_t)N * sizeof(int), stream);
    hist_k<<<gE, TPB, 0, stream>>>(dst, deg, E);
    scan_a_k<<<nb, TPB, 0, stream>>>(deg, N, incl, bsum);
    scan_b_k<<<1, TPB, 0, stream>>>(bsum, nb);
    finalize_k<<<nb, TPB, 0, stream>>>(incl, deg, bsum, N, row_ptr, cursor);
    scatter_k<<<gE, TPB, 0, stream>>>(src, dst, ea, cursor, csr_src, csr_ea, E);

    // ---- packs + input convert ----
    prepack_k<<<65536 / TPB, TPB, 0, stream>>>(Wq1, Wk1, Wv1, Ws1, pk1);
    prepack_k<<<65536 / TPB, TPB, 0, stream>>>(Wq2, Wk2, Wv2, Ws2, pk2);
    cvt_bf16_k<<<gCv, TPB, 0, stream>>>(x, xb, N * 128 / 4);

    // ---- layer 1 ----
    gemm_mfma_k<<<gG, TPB, 0, stream>>>(xb, N, pk1, bq1, bk1, bv1, bs1, q, k, v, s);
    node_attn_k<true><<<gN4, TPB, 0, stream>>>(q, k, v, s, We1, row_ptr, csr_src,
                                               csr_ea, xb, N);  // h -> bf16 (reuse xb)
    // ---- layer 2 ----
    gemm_mfma_k<<<gG, TPB, 0, stream>>>(xb, N, pk2, bq2, bk2, bv2, bs2, q, k, v, s);
    node_attn_k<false><<<gN4, TPB, 0, stream>>>(q, k, v, s, We2, row_ptr, csr_src,
                                                csr_ea, outf, N);
}